// Round 1
// 447.964 us; speedup vs baseline: 1.1698x; 1.1698x over previous
//
#include <hip/hip_runtime.h>
#include <stdint.h>

// ---------------------------------------------------------------------------
// DQN hypergraph pipeline, round 5: occupancy + pipelining rewrite.
//
// r4 counters: big_gemm at 10% occupancy (256 blocks = 1 block/CU, 1
// wave/SIMD), MfmaUtil 8%, HBM 16% -> latency-bound. Changes:
//  * big_gemm: 512 threads (8 waves), split-K SA 16 / SB 8 -> 512 blocks =
//    2 blocks/CU = 16 waves/CU. Register prefetch of next K-tile + LDS
//    double-buffer with a single barrier per K-step.
//  * small_gemm pair fused into one launch via blockIdx.y; bias folded
//    into Badd epilogue.
//  * reduce_A re-tiled to 16 edge-rows/block (256 blocks) for SA=16.
// Numerics (bf16 hi/lo split, threefry dropout) unchanged from r4.
// ws use: P 33.5MB + 14.5MB rest (fill evidence says ws = 512MB).
// ---------------------------------------------------------------------------

typedef short short8 __attribute__((ext_vector_type(8)));
typedef float f32x4 __attribute__((ext_vector_type(4)));

static constexpr int N = 8192, E = 4096, F = 128;
static constexpr int SA = 16, SB = 8;  // split-K factors (chunk = 512 both)

__device__ __forceinline__ unsigned rotl32(unsigned x, int r) {
  return (x << r) | (x >> (32 - r));
}

__device__ __forceinline__ uint2 threefry2x32(unsigned k0, unsigned k1,
                                              unsigned x0, unsigned x1) {
  unsigned ks[3] = {k0, k1, k0 ^ k1 ^ 0x1BD11BDAu};
  x0 += ks[0];
  x1 += ks[1];
  const int R0[4] = {13, 15, 26, 6};
  const int R1[4] = {17, 29, 16, 24};
#pragma unroll
  for (int i = 0; i < 5; ++i) {
#pragma unroll
    for (int j = 0; j < 4; ++j) {
      const int r = (i % 2 == 0) ? R0[j] : R1[j];
      x0 += x1;
      x1 = rotl32(x1, r);
      x1 ^= x0;
    }
    x0 += ks[(i + 1) % 3];
    x1 += ks[(i + 2) % 3] + (unsigned)(i + 1);
  }
  return make_uint2(x0, x1);
}

// jax partitionable threefry bernoulli: bits = out.x ^ out.y, keep <=> MSB==0
__device__ __forceinline__ float drop_scale(unsigned idx) {
  const uint2 o = threefry2x32(0u, 42u, 0u, idx);
  return ((o.x ^ o.y) & 0x80000000u) ? 0.0f : 2.0f;
}

__device__ __forceinline__ float lrelu(float v) {
  return v >= 0.0f ? v : 0.01f * v;
}

__device__ __forceinline__ unsigned rne1(float a) {  // f32 -> bf16 (low 16)
  unsigned ua = __builtin_bit_cast(unsigned, a);
  ua += 0x7fffu + ((ua >> 16) & 1u);
  return ua >> 16;
}
__device__ __forceinline__ float bf16_val(unsigned u16) {
  return __builtin_bit_cast(float, u16 << 16);
}
__device__ __forceinline__ unsigned pk_bf16(float a, float b) {
  return rne1(a) | (rne1(b) << 16);
}
// hi/lo packed pair for (a,b)
__device__ __forceinline__ void split2(float a, float b, unsigned& hi,
                                       unsigned& lo) {
  const unsigned ha = rne1(a), hb = rne1(b);
  const float ra = a - bf16_val(ha), rb = b - bf16_val(hb);
  hi = ha | (hb << 16);
  lo = rne1(ra) | (rne1(rb) << 16);
}

// ---------------------------------------------------------------------------
// Big split-K GEMM. 128x128 tile, BK=32, 512 threads = 8 waves (4 row x 2
// col, 32x64 per wave). Register prefetch + LDS double-buffer, one barrier
// per K-step. TRANSA=0: A fp32 [M][K] (Hs), lda=K. TRANSA=1: A fp32
// [K][Mfull] (Ht), lda=N. Bt fp32 [128][K] k-contiguous; B staged hi/lo.
// ---------------------------------------------------------------------------
template <bool TRANSA>
__global__ __launch_bounds__(512, 4) void big_gemm(
    const float* __restrict__ A, const float* __restrict__ Bt,
    float* __restrict__ P, int M, int K, int lda, int kchunk) {
  __shared__ __align__(16) short As[2][128 * 40];
  __shared__ __align__(16) short Bh[2][128 * 40];
  __shared__ __align__(16) short Bl[2][128 * 40];

  const int tid = threadIdx.x;
  const int lane = tid & 63;
  const int w = tid >> 6;        // 0..7
  const int wm = (w & 3) << 5;   // 0,32,64,96
  const int wn = (w >> 2) << 6;  // 0,64
  const int l15 = lane & 15;
  const int koff = (lane >> 4) << 3;  // shorts

  const int r0 = blockIdx.x * 128;
  const int s = blockIdx.y;
  const int kbeg = s * kchunk;
  const int nt = kchunk >> 5;

  float4 ra[2], rb[2];

  auto loadg = [&](int kt) {
    if (!TRANSA) {
#pragma unroll
      for (int i = 0; i < 2; ++i) {
        const int f = i * 512 + tid;  // 0..1023
        const int m = f >> 3;
        const int kq = f & 7;
        ra[i] = *(const float4*)(A + (size_t)(r0 + m) * lda + kt + 4 * kq);
      }
    } else {
      const int m = tid & 127;
      const int eo = tid >> 7;  // 0..3
      float* v = (float*)ra;
#pragma unroll
      for (int r = 0; r < 8; ++r)
        v[r] = A[(size_t)(kt + 8 * eo + r) * lda + r0 + m];
    }
#pragma unroll
    for (int i = 0; i < 2; ++i) {
      const int q = i * 512 + tid;  // 0..1023
      const int c = q >> 3;
      const int kq = q & 7;
      rb[i] = *(const float4*)(Bt + (size_t)c * K + kt + 4 * kq);
    }
  };

  auto store_lds = [&](int buf) {
    if (!TRANSA) {
#pragma unroll
      for (int i = 0; i < 2; ++i) {
        const int f = i * 512 + tid;
        const int m = f >> 3;
        const int kq = f & 7;
        uint2 u = {pk_bf16(ra[i].x, ra[i].y), pk_bf16(ra[i].z, ra[i].w)};
        *(uint2*)&As[buf][m * 40 + 4 * kq] = u;
      }
    } else {
      const int m = tid & 127;
      const int eo = tid >> 7;
      const float* v = (const float*)ra;
      uint4 u = {pk_bf16(v[0], v[1]), pk_bf16(v[2], v[3]),
                 pk_bf16(v[4], v[5]), pk_bf16(v[6], v[7])};
      *(uint4*)&As[buf][m * 40 + 8 * eo] = u;
    }
#pragma unroll
    for (int i = 0; i < 2; ++i) {
      const int q = i * 512 + tid;
      const int c = q >> 3;
      const int kq = q & 7;
      uint2 uh, ul;
      split2(rb[i].x, rb[i].y, uh.x, ul.x);
      split2(rb[i].z, rb[i].w, uh.y, ul.y);
      *(uint2*)&Bh[buf][c * 40 + 4 * kq] = uh;
      *(uint2*)&Bl[buf][c * 40 + 4 * kq] = ul;
    }
  };

  f32x4 acc[2][4];
#pragma unroll
  for (int i = 0; i < 2; ++i)
#pragma unroll
    for (int j = 0; j < 4; ++j) acc[i][j] = (f32x4){0.f, 0.f, 0.f, 0.f};

  loadg(kbeg);
  store_lds(0);
  int cur = 0;
  for (int t = 0; t < nt; ++t) {
    __syncthreads();  // buf[cur] ready for all waves
    if (t + 1 < nt) loadg(kbeg + 32 * (t + 1));  // issue next tile early

    short8 af[2], bhf[4], blf[4];
#pragma unroll
    for (int i = 0; i < 2; ++i)
      af[i] = *(const short8*)&As[cur][(wm + 16 * i + l15) * 40 + koff];
#pragma unroll
    for (int j = 0; j < 4; ++j) {
      bhf[j] = *(const short8*)&Bh[cur][(wn + 16 * j + l15) * 40 + koff];
      blf[j] = *(const short8*)&Bl[cur][(wn + 16 * j + l15) * 40 + koff];
    }
#pragma unroll
    for (int i = 0; i < 2; ++i)
#pragma unroll
      for (int j = 0; j < 4; ++j) {
        acc[i][j] = __builtin_amdgcn_mfma_f32_16x16x32_bf16(af[i], blf[j],
                                                            acc[i][j], 0, 0, 0);
        acc[i][j] = __builtin_amdgcn_mfma_f32_16x16x32_bf16(af[i], bhf[j],
                                                            acc[i][j], 0, 0, 0);
      }
    // pack prefetched regs into the other buffer; its last readers finished
    // before the barrier at the top of this iteration -> WAR-safe.
    if (t + 1 < nt) store_lds(cur ^ 1);
    cur ^= 1;
  }

  const int rquad = (lane >> 4) << 2;
#pragma unroll
  for (int i = 0; i < 2; ++i)
#pragma unroll
    for (int j = 0; j < 4; ++j)
#pragma unroll
      for (int r = 0; r < 4; ++r) {
        const int row = r0 + wm + 16 * i + rquad + r;
        const int col = wn + 16 * j + l15;
        P[((size_t)s * M + row) * 128 + col] = acc[i][j][r];
      }
}

// ---------------------------------------------------------------------------
// Fused small GEMMs vs 128x128 weights, K=128, BK=32, both operands hi/lo.
// blockIdx.y==0: Tt[c][n] = (srcT @ Wth)^T.  blockIdx.y==1:
// Badd[n][c] = srcB @ Wwt + bias (bias folded here).
// ---------------------------------------------------------------------------
template <bool WA>
__device__ __forceinline__ void small_core(
    const float* __restrict__ src, const float* __restrict__ W,
    const float* __restrict__ bias, float* __restrict__ out, short* WTh,
    short* WTl, short* Xh, short* Xl, int n0, int tid) {
  constexpr int TI = WA ? 4 : 2;
  constexpr int TJ = WA ? 2 : 4;
  const int lane = tid & 63;
  const int w = tid >> 6;
  const int l15 = lane & 15;
  const int wm = (w & 1) * (WA ? 64 : 32);
  const int wn = (w >> 1) * (WA ? 32 : 64);

  f32x4 acc[TI][TJ];
#pragma unroll
  for (int i = 0; i < TI; ++i)
#pragma unroll
    for (int j = 0; j < TJ; ++j) acc[i][j] = (f32x4){0.f, 0.f, 0.f, 0.f};

  for (int k0 = 0; k0 < 128; k0 += 32) {
    // stage W chunk transposed: WT[c][k] = W[k0+k][c], hi/lo
#pragma unroll
    for (int i = 0; i < 2; ++i) {
      const int f = i * 256 + tid;  // 0..511
      const int c = f & 127;
      const int eo = f >> 7;  // 0..3
      uint4 uh, ul;
      unsigned* ph = (unsigned*)&uh;
      unsigned* pl = (unsigned*)&ul;
#pragma unroll
      for (int r = 0; r < 4; ++r) {
        const float a = W[(size_t)(k0 + 8 * eo + 2 * r) * 128 + c];
        const float b = W[(size_t)(k0 + 8 * eo + 2 * r + 1) * 128 + c];
        split2(a, b, ph[r], pl[r]);
      }
      *(uint4*)&WTh[c * 40 + 8 * eo] = uh;
      *(uint4*)&WTl[c * 40 + 8 * eo] = ul;
    }
    // stage src chunk: X[n][k], hi/lo
#pragma unroll
    for (int i = 0; i < 2; ++i) {
      const int q = i * 256 + tid;  // 0..511
      const int n = q >> 3;         // 0..63
      const int kq = q & 7;
      const float4 v =
          *(const float4*)(src + (size_t)(n0 + n) * 128 + k0 + 4 * kq);
      uint2 uh, ul;
      split2(v.x, v.y, uh.x, ul.x);
      split2(v.z, v.w, uh.y, ul.y);
      *(uint2*)&Xh[n * 40 + 4 * kq] = uh;
      *(uint2*)&Xl[n * 40 + 4 * kq] = ul;
    }
    __syncthreads();

    const int koff = (lane >> 4) << 3;
    short8 ah[TI], al[TI], bh[TJ], bl[TJ];
#pragma unroll
    for (int i = 0; i < TI; ++i) {
      const int m = wm + 16 * i + l15;
      ah[i] = WA ? *(const short8*)&WTh[m * 40 + koff]
                 : *(const short8*)&Xh[m * 40 + koff];
      al[i] = WA ? *(const short8*)&WTl[m * 40 + koff]
                 : *(const short8*)&Xl[m * 40 + koff];
    }
#pragma unroll
    for (int j = 0; j < TJ; ++j) {
      const int c = wn + 16 * j + l15;
      bh[j] = WA ? *(const short8*)&Xh[c * 40 + koff]
                 : *(const short8*)&WTh[c * 40 + koff];
      bl[j] = WA ? *(const short8*)&Xl[c * 40 + koff]
                 : *(const short8*)&WTl[c * 40 + koff];
    }
#pragma unroll
    for (int i = 0; i < TI; ++i)
#pragma unroll
      for (int j = 0; j < TJ; ++j) {
        acc[i][j] = __builtin_amdgcn_mfma_f32_16x16x32_bf16(al[i], bh[j],
                                                            acc[i][j], 0, 0, 0);
        acc[i][j] = __builtin_amdgcn_mfma_f32_16x16x32_bf16(ah[i], bl[j],
                                                            acc[i][j], 0, 0, 0);
        acc[i][j] = __builtin_amdgcn_mfma_f32_16x16x32_bf16(ah[i], bh[j],
                                                            acc[i][j], 0, 0, 0);
      }
    __syncthreads();
  }

  const int rquad = (lane >> 4) << 2;
#pragma unroll
  for (int i = 0; i < TI; ++i)
#pragma unroll
    for (int j = 0; j < TJ; ++j)
#pragma unroll
      for (int r = 0; r < 4; ++r) {
        const int row = wm + 16 * i + rquad + r;
        const int col = wn + 16 * j + l15;
        if constexpr (WA)  // Tt[c][n], coalesced over n
          out[(size_t)row * N + n0 + col] = acc[i][j][r];
        else  // Badd[n][c] + bias
          out[(size_t)(n0 + row) * 128 + col] = acc[i][j][r] + bias[col];
      }
}

__global__ __launch_bounds__(256) void small_fused(
    const float* __restrict__ srcT, const float* __restrict__ Wth,
    const float* __restrict__ srcB, const float* __restrict__ Wwt,
    const float* __restrict__ bias, float* __restrict__ Tt,
    float* __restrict__ Badd) {
  __shared__ __align__(16) short WTh[128 * 40], WTl[128 * 40];
  __shared__ __align__(16) short Xh[64 * 40], Xl[64 * 40];
  const int n0 = blockIdx.x * 64;
  if (blockIdx.y == 0)  // block-uniform branch; barriers inside are safe
    small_core<true>(srcT, Wth, nullptr, Tt, WTh, WTl, Xh, Xl, n0,
                     threadIdx.x);
  else
    small_core<false>(srcB, Wwt, bias, Badd, WTh, WTl, Xh, Xl, n0,
                      threadIdx.x);
}

// Mt[c][e] = ew[e] * sum_s P[s][e][c];  P [SA][E][128], 16 e-rows per block
__global__ __launch_bounds__(256) void reduce_A(const float* __restrict__ P,
                                                const float* __restrict__ ew,
                                                float* __restrict__ Mt) {
  __shared__ float Lt[16 * 132];
  const int tid = threadIdx.x;
  const int e0 = blockIdx.x * 16;
#pragma unroll
  for (int i = 0; i < 2; ++i) {
    const int f = i * 256 + tid;  // 0..511
    const int el = f >> 5;        // 0..15
    const int cq = f & 31;
    float4 a = {0.f, 0.f, 0.f, 0.f};
#pragma unroll
    for (int s = 0; s < SA; ++s) {
      const float4 v =
          *(const float4*)(P + ((size_t)s * E + e0 + el) * 128 + 4 * cq);
      a.x += v.x; a.y += v.y; a.z += v.z; a.w += v.w;
    }
    const float sc = ew[e0 + el];
    a.x *= sc; a.y *= sc; a.z *= sc; a.w *= sc;
    *(float4*)&Lt[el * 132 + 4 * cq] = a;
  }
  __syncthreads();
#pragma unroll
  for (int i = 0; i < 2; ++i) {
    const int g = i * 256 + tid;  // 0..511
    const int c = g >> 2;         // 0..127
    const int eq = g & 3;
    float4 o;
    o.x = Lt[(4 * eq + 0) * 132 + c];
    o.y = Lt[(4 * eq + 1) * 132 + c];
    o.z = Lt[(4 * eq + 2) * 132 + c];
    o.w = Lt[(4 * eq + 3) * 132 + c];
    *(float4*)&Mt[(size_t)c * E + e0 + 4 * eq] = o;
  }
}

// X1[n][c] = dropout(lrelu(sum_s P + Badd));  P [SB][N][128]; bias in Badd
__global__ __launch_bounds__(256) void reduce_B1(const float* __restrict__ P,
                                                 const float* __restrict__ Badd,
                                                 float* __restrict__ X1) {
  const int q = blockIdx.x * 256 + threadIdx.x;
  const int n = q >> 5;
  const int cq = q & 31;
  float4 a = {0.f, 0.f, 0.f, 0.f};
#pragma unroll
  for (int s = 0; s < SB; ++s) {
    const float4 v = *(const float4*)(P + ((size_t)s * N + n) * 128 + 4 * cq);
    a.x += v.x; a.y += v.y; a.z += v.z; a.w += v.w;
  }
  const float4 b = *(const float4*)(Badd + (size_t)n * 128 + 4 * cq);
  const unsigned fb = (unsigned)(n * 128 + 4 * cq);
  float4 o;
  o.x = lrelu(a.x + b.x) * drop_scale(fb + 0u);
  o.y = lrelu(a.y + b.y) * drop_scale(fb + 1u);
  o.z = lrelu(a.z + b.z) * drop_scale(fb + 2u);
  o.w = lrelu(a.w + b.w) * drop_scale(fb + 3u);
  *(float4*)&X1[(size_t)n * 128 + 4 * cq] = o;
}

// out[n] = sum_c lrelu(lrelu(sum_s P + Badd)) * fcw[c]
//          + state[n]*fcw[128] + fcb[0]   (bias folded into Badd)
__global__ __launch_bounds__(256) void reduce_B2(
    const float* __restrict__ P, const float* __restrict__ Badd,
    const float* __restrict__ fcw, const float* __restrict__ state,
    const float* __restrict__ fcb, float* __restrict__ out) {
  __shared__ float part[4];
  const int tid = threadIdx.x;
  const int nn = tid >> 7;
  const int c = tid & 127;
  const int n = blockIdx.x * 2 + nn;
  float v = 0.f;
#pragma unroll
  for (int s = 0; s < SB; ++s) v += P[((size_t)s * N + n) * 128 + c];
  v += Badd[(size_t)n * 128 + c];
  float p = lrelu(lrelu(v)) * fcw[c];
#pragma unroll
  for (int m = 32; m >= 1; m >>= 1) p += __shfl_xor(p, m, 64);
  if ((tid & 63) == 0) part[tid >> 6] = p;
  __syncthreads();
  if (tid < 2)
    out[blockIdx.x * 2 + tid] = part[2 * tid] + part[2 * tid + 1] +
                                state[blockIdx.x * 2 + tid] * fcw[128] + fcb[0];
}

extern "C" void kernel_launch(void* const* d_in, const int* in_sizes, int n_in,
                              void* d_out, int out_size, void* d_ws,
                              size_t ws_size, hipStream_t stream) {
  (void)in_sizes; (void)n_in; (void)out_size; (void)ws_size;

  const float* xi = (const float*)d_in[0];
  const float* x = (const float*)d_in[1];
  const float* Ht = (const float*)d_in[2];   // [E][N]
  const float* Hs = (const float*)d_in[3];   // [E][N]
  const float* state = (const float*)d_in[4];
  const float* wt0 = (const float*)d_in[5];
  const float* th0 = (const float*)d_in[6];
  const float* ew0 = (const float*)d_in[7];
  const float* bi0 = (const float*)d_in[8];
  const float* wt1 = (const float*)d_in[9];
  const float* th1 = (const float*)d_in[10];
  const float* ew1 = (const float*)d_in[11];
  const float* bi1 = (const float*)d_in[12];
  const float* fcw = (const float*)d_in[13];  // [129]
  const float* fcb = (const float*)d_in[14];  // [1]
  float* out = (float*)d_out;                 // [8192]

  // ws layout (floats): P[8.39M] | Tt[1M] | Badd[1M] | Mt[512K] | X1[1M]
  // = 48.2 MB (fill evidence: ws is 512MB)
  float* ws = (float*)d_ws;
  float* P = ws;
  float* Tt = P + (size_t)SA * E * F;   // SA*E*128 == SB*N*128 == 8388608
  float* Badd = Tt + (size_t)F * N;
  float* Mt = Badd + (size_t)N * F;
  float* X1 = Mt + (size_t)F * E;

  // ---- layer 1 ----
  small_fused<<<dim3(N / 64, 2), 256, 0, stream>>>(x, th0, xi, wt0, bi0, Tt,
                                                   Badd);
  big_gemm<false><<<dim3(E / 128, SA), 512, 0, stream>>>(Hs, Tt, P, E, N, N,
                                                         N / SA);
  reduce_A<<<E / 16, 256, 0, stream>>>(P, ew0, Mt);
  big_gemm<true><<<dim3(N / 128, SB), 512, 0, stream>>>(Ht, Mt, P, N, E, N,
                                                        E / SB);
  reduce_B1<<<N * F / 4 / 256, 256, 0, stream>>>(P, Badd, X1);

  // ---- layer 2 + head ----
  small_fused<<<dim3(N / 64, 2), 256, 0, stream>>>(X1, th1, xi, wt1, bi1, Tt,
                                                   Badd);
  big_gemm<false><<<dim3(E / 128, SA), 512, 0, stream>>>(Hs, Tt, P, E, N, N,
                                                         N / SA);
  reduce_A<<<E / 16, 256, 0, stream>>>(P, ew1, Mt);
  big_gemm<true><<<dim3(N / 128, SB), 512, 0, stream>>>(Ht, Mt, P, N, E, N,
                                                        E / SB);
  reduce_B2<<<N / 2, 256, 0, stream>>>(P, Badd, fcw, state, fcb, out);
}